// Round 10
// baseline (6549.423 us; speedup 1.0000x reference)
//
#include <hip/hip_runtime.h>
#include <hip/hip_bf16.h>

#define NB   32
#define HH   1024
#define LL   512
#define KTOT 2048

typedef __bf16 bf8 __attribute__((ext_vector_type(8)));
typedef float  f4  __attribute__((ext_vector_type(4)));
typedef unsigned short us8 __attribute__((ext_vector_type(8)));

#define MFMA(a, b, c) __builtin_amdgcn_mfma_f32_16x16x32_bf16( \
    __builtin_bit_cast(bf8, a), __builtin_bit_cast(bf8, b), c, 0, 0, 0)

// Software round-to-nearest-even f32 -> bf16 (R1/R5/R8/R9-proven numerics)
__device__ __forceinline__ unsigned short f2bf(float f) {
  unsigned u = __builtin_bit_cast(unsigned, f);
  u += 0x7fffu + ((u >> 16) & 1u);
  return (unsigned short)(u >> 16);
}
__device__ __forceinline__ us8 pack8(f4 a, f4 b) {
  us8 r;
  r[0]=f2bf(a[0]); r[1]=f2bf(a[1]); r[2]=f2bf(a[2]); r[3]=f2bf(a[3]);
  r[4]=f2bf(b[0]); r[5]=f2bf(b[1]); r[6]=f2bf(b[2]); r[7]=f2bf(b[3]);
  return r;
}

// FROZEN sync primitive (R1/R5/R8/R9-proven): per-lane ACQUIRE spin on a 64B
// sub-counter line; callers follow with __syncthreads, then plain loads.
__device__ __forceinline__ void spinA(unsigned* p, unsigned tgt) {
  while (__hip_atomic_load(p, __ATOMIC_ACQUIRE, __HIP_MEMORY_SCOPE_AGENT) < tgt)
    __builtin_amdgcn_s_sleep(8);
}
// Write-through data store (R9-proven): agent-scope relaxed atomic store lands
// at the coherence point; release's wbl2 then finds ~no dirty lines.
__device__ __forceinline__ void stwt(unsigned* p, unsigned v) {
  __hip_atomic_store(p, v, __ATOMIC_RELAXED, __HIP_MEMORY_SCOPE_AGENT);
}

// ---- optional pre-pass (only if ws_size allows): x0[t][n][h] = bf16(emb[tokens]) ----
__global__ void __launch_bounds__(256)
prepack(const int* __restrict__ tokens, const float* __restrict__ emb,
        unsigned short* __restrict__ x0) {
  int idx = blockIdx.x * 256 + threadIdx.x;     // 32*512*128 = 2,097,152
  int n  = idx >> 16;
  int t  = (idx >> 7) & 511;
  int h  = (idx & 127) << 3;
  int row = tokens[n * LL + t];
  const float* src = emb + (size_t)row * HH + h;
  *(us8*)(x0 + ((size_t)t * NB + n) * HH + h) = pack8(*(const f4*)src, *(const f4*)(src + 4));
}

// ---- persistent dataflow LSTM: 256 WGs x 256 thr. WG w: layer=w>>7, h-octet w&127.
// NEW wave decomposition (kh-split, dedups A loads 2x): wave wid: nh=wid>>1 (batch
// rows nh*16..+16), kh=wid&1 (K-half). Each wave loads its DISJOINT A K-half and
// computes BOTH jh B-halves from LDS; kh partials summed in LDS at update phase.
__global__ void __launch_bounds__(256, 1)
lstm_persist(const int* __restrict__ tokens, const float* __restrict__ emb,
             const float* __restrict__ W, const float* __restrict__ Bb,
             float* __restrict__ out, unsigned* flags, unsigned short* s1,
             unsigned short* s2, const unsigned short* x0)
{
  // wlds fragment order: slot(jh, cm, lane) = jh*4096 + cm*64 + lane (8 bf16 each):
  // W row j = jh*16+(lane&15), k = cm*32 + (lane>>4)*8 .. +8 -> lane-linear ds_read_b128
  __shared__ unsigned short wlds[65536];     // 128 KiB
  __shared__ float glds[2 * 32 * 36];        // [kh][n][j] stride-36 pad, 9 KiB
  __shared__ float bias[32];

  const int tid   = threadIdx.x;
  const int layer = blockIdx.x >> 7;
  const int wg    = blockIdx.x & 127;
  const int h0    = wg * 8;
  // sub-counter layout: cnt[layer][t][sub], sub-stride 16 dwords (64B line)
  unsigned* cnt1  = flags;                  // layer-0: 512 steps x 8 subs x 16
  unsigned* cnt2  = flags + 512 * 128;      // layer-1
  unsigned* mycnt = layer ? cnt2 : cnt1;
  const int mysub = (wg & 7) * 16;

  // one-time: W slice (32 rows x 2048 f32, coalesced) -> fragment-ordered bf16 LDS
  for (int it = 0; it < 32; ++it) {
    int e = (it * 256 + tid) * 8;
    int r = e >> 11;                       // local row: gate = r>>3, i = r&7
    int k = e & 2047;
    const float* src = W + (((size_t)layer * 4 + (r >> 3)) * HH + (h0 + (r & 7))) * (size_t)KTOT + k;
    int slot = ((r >> 4) << 12) + (((k >> 8) * 8 + ((k >> 5) & 7)) << 6) + (r & 15) + (((k >> 3) & 3) << 4);
    *(us8*)&wlds[(unsigned)slot * 8] = pack8(*(const f4*)src, *(const f4*)(src + 4));
  }
  if (tid < 32) bias[tid] = Bb[((size_t)layer * 4 + (tid >> 3)) * HH + h0 + (tid & 7)];
  __syncthreads();

  const int lane = tid & 63;
  const int wid  = tid >> 6;
  const int nh = wid >> 1, kh = wid & 1;
  const int arow = nh * 16 + (lane & 15);        // batch row for A fragments
  const int rb   = (lane >> 4) * 8;              // k-slice within 32-wide K step
  const unsigned short* wb0 = &wlds[(unsigned)lane * 8u];          // jh=0 fragments
  const unsigned short* wb1 = wb0 + 32768;                         // jh=1 fragments

  float lng = 0.f;                               // cell state (n=tid>>3, h=h0+(tid&7))

  // ---- epilogue shared by both layers (scatter kh-partials, update, store) ----
  auto epilogue = [&](int t, f4 a0, f4 a1) {
    int grow = nh * 16 + ((lane >> 4) << 2);
    int col  = lane & 15;
    #pragma unroll
    for (int r = 0; r < 4; ++r) {
      glds[kh * 1152 + (grow + r) * 36 + col]      = a0[r];
      glds[kh * 1152 + (grow + r) * 36 + col + 16] = a1[r];
    }
    __syncthreads();
    {
      int n = tid >> 3, i = tid & 7;
      const float* g0 = glds + n * 36;
      float gf = g0[ 0 + i] + g0[1152 +  0 + i] + bias[ 0 + i];
      float gi = g0[ 8 + i] + g0[1152 +  8 + i] + bias[ 8 + i];
      float go = g0[16 + i] + g0[1152 + 16 + i] + bias[16 + i];
      float gc = g0[24 + i] + g0[1152 + 24 + i] + bias[24 + i];
      float fg = 1.f / (1.f + __expf(-gf));
      float ig = 1.f / (1.f + __expf(-gi));
      float og = 1.f / (1.f + __expf(-go));
      lng = fg * lng + ig * gc;                   // cand raw (matches reference)
      float a  = fabsf(lng);
      float e  = __expf(-2.f * a);
      float th = __builtin_copysignf((1.f - e) / (1.f + e), lng);
      float sh = og * th;
      unsigned v16 = f2bf(sh);
      unsigned nb  = __shfl_down(v16, 1);
      unsigned pair = v16 | (nb << 16);
      if (layer == 0) {
        if (!(i & 1))
          stwt((unsigned*)(s1 + ((size_t)t * NB + n) * HH + h0 + i), pair);
      } else {
        stwt((unsigned*)(out + ((size_t)n * LL + t) * HH + h0 + i),
             __builtin_bit_cast(unsigned, sh));
        if (s2 && !(i & 1))
          stwt((unsigned*)(s2 + ((size_t)t * NB + n) * HH + h0 + i), pair);
      }
    }
    __syncthreads();   // vmcnt(0) per wave: all write-through stores accepted
    if (tid == 0)
      __hip_atomic_fetch_add(mycnt + (size_t)t * 128 + mysub, 1u,
                             __ATOMIC_RELEASE, __HIP_MEMORY_SCOPE_AGENT);
  };

  if (layer == 0) {
    us8 nfA[16], nfB[16];
    auto loadNF = [&](us8 (&dst)[16], int t) {
      if (x0) {
        const unsigned short* base = x0 + ((size_t)t * NB + arow) * HH + kh * 512 + rb;
        #pragma unroll
        for (int f = 0; f < 16; ++f)
          dst[f] = *(const us8*)(base + (f >> 3) * 256 + (f & 7) * 32);
      } else {
        const float* base = emb + (size_t)tokens[arow * LL + t] * HH + kh * 512 + rb;
        #pragma unroll
        for (int f = 0; f < 16; ++f)
          dst[f] = pack8(*(const f4*)(base + (f >> 3) * 256 + (f & 7) * 32),
                         *(const f4*)(base + (f >> 3) * 256 + (f & 7) * 32 + 4));
      }
    };

    loadNF(nfA, 0);
    for (int t = 0; t < LL; ++t) {
      if (t + 1 < LL) loadNF(nfB, t + 1);        // prefetch: overlaps MFMAs + wait
      f4 a0 = {0.f,0.f,0.f,0.f}, a1 = {0.f,0.f,0.f,0.f};
      f4 r0 = {0.f,0.f,0.f,0.f}, r1 = {0.f,0.f,0.f,0.f};
      // now-half: B slots 32 + kh*16 + f
      #pragma unroll
      for (int f = 0; f < 16; ++f) {
        a0 = MFMA(nfA[f], *(const us8*)(wb0 + (32 + kh * 16 + f) * 512), a0);
        a1 = MFMA(nfA[f], *(const us8*)(wb1 + (32 + kh * 16 + f) * 512), a1);
      }
      if (t + 1 < LL) {                          // pin prefetch before the wait
        #pragma unroll
        for (int f = 0; f < 16; ++f)
          asm volatile("" :: "v"((unsigned)nfB[f][0]));
      }
      if (t > 0) {
        if (tid < 8) spinA(cnt1 + (size_t)(t - 1) * 128 + tid * 16, 16);
        __syncthreads();
        const unsigned short* base = s1 + ((size_t)(t - 1) * NB + arow) * HH + kh * 512 + rb;
        #pragma unroll
        for (int f = 0; f < 16; ++f) {
          us8 v = *(const us8*)(base + (f >> 3) * 256 + (f & 7) * 32);
          r0 = MFMA(v, *(const us8*)(wb0 + (kh * 16 + f) * 512), r0);
          r1 = MFMA(v, *(const us8*)(wb1 + (kh * 16 + f) * 512), r1);
        }
      }
      epilogue(t, a0 + r0, a1 + r1);
      if (t + 1 < LL) {
        #pragma unroll
        for (int f = 0; f < 16; ++f) nfA[f] = nfB[f];
      }
    }
  } else {
    for (int t = 0; t < LL; ++t) {
      // merged single wait: lanes 0-7 watch cnt1[t], lanes 8-15 watch cnt2[t-1]
      if (tid < 8)                 spinA(cnt1 + (size_t)t * 128 + tid * 16, 16);
      else if (tid < 16 && t > 0)  spinA(cnt2 + (size_t)(t - 1) * 128 + (tid - 8) * 16, 16);
      __syncthreads();
      f4 a0 = {0.f,0.f,0.f,0.f}, a1 = {0.f,0.f,0.f,0.f};
      f4 r0 = {0.f,0.f,0.f,0.f}, r1 = {0.f,0.f,0.f,0.f};
      {
        const unsigned short* base = s1 + ((size_t)t * NB + arow) * HH + kh * 512 + rb;
        #pragma unroll
        for (int f = 0; f < 16; ++f) {
          us8 v = *(const us8*)(base + (f >> 3) * 256 + (f & 7) * 32);
          a0 = MFMA(v, *(const us8*)(wb0 + (32 + kh * 16 + f) * 512), a0);
          a1 = MFMA(v, *(const us8*)(wb1 + (32 + kh * 16 + f) * 512), a1);
        }
      }
      if (t > 0) {
        if (s2) {
          const unsigned short* base = s2 + ((size_t)(t - 1) * NB + arow) * HH + kh * 512 + rb;
          #pragma unroll
          for (int f = 0; f < 16; ++f) {
            us8 v = *(const us8*)(base + (f >> 3) * 256 + (f & 7) * 32);
            r0 = MFMA(v, *(const us8*)(wb0 + (kh * 16 + f) * 512), r0);
            r1 = MFMA(v, *(const us8*)(wb1 + (kh * 16 + f) * 512), r1);
          }
        } else {
          const float* base = out + ((size_t)arow * LL + (t - 1)) * HH + kh * 512 + rb;
          #pragma unroll
          for (int f = 0; f < 16; ++f) {
            us8 v = pack8(*(const f4*)(base + (f >> 3) * 256 + (f & 7) * 32),
                          *(const f4*)(base + (f >> 3) * 256 + (f & 7) * 32 + 4));
            r0 = MFMA(v, *(const us8*)(wb0 + (kh * 16 + f) * 512), r0);
            r1 = MFMA(v, *(const us8*)(wb1 + (kh * 16 + f) * 512), r1);
          }
        }
      }
      epilogue(t, a0 + r0, a1 + r1);
    }
  }
}

extern "C" void kernel_launch(void* const* d_in, const int* in_sizes, int n_in,
                              void* d_out, int out_size, void* d_ws, size_t ws_size,
                              hipStream_t stream) {
  const int*   tokens = (const int*)d_in[0];
  const float* emb    = (const float*)d_in[1];
  const float* W      = (const float*)d_in[2];
  const float* Bb     = (const float*)d_in[3];
  float*       out    = (float*)d_out;

  // ws layout:
  //   [0, 512KB)    sub-counters: cnt[2][512][8] on separate 64B lines
  //   [512KB,+32MB) s1 bf16 [512][32][1024]                    (required)
  //   optional s2 (layer-1 bf16 state), optional x0 (prepacked emb)
  const size_t FL = 524288;
  const size_t SZ = (size_t)LL * NB * HH * sizeof(unsigned short);   // 32 MiB
  unsigned*       flags = (unsigned*)d_ws;
  unsigned short* s1    = (unsigned short*)((char*)d_ws + FL);
  unsigned short* s2    = (ws_size >= FL + 2 * SZ) ? (unsigned short*)((char*)d_ws + FL + SZ) : nullptr;
  unsigned short* x0    = (ws_size >= FL + 3 * SZ) ? (unsigned short*)((char*)d_ws + FL + 2 * SZ) : nullptr;

  hipMemsetAsync(d_ws, 0, FL, stream);   // zero counters every replay (graph-captured)
  if (x0) prepack<<<dim3(8192), dim3(256), 0, stream>>>(tokens, emb, x0);

  void* args[] = { (void*)&tokens, (void*)&emb, (void*)&W, (void*)&Bb,
                   (void*)&out, (void*)&flags, (void*)&s1, (void*)&s2, (void*)&x0 };
  hipLaunchCooperativeKernel((void*)lstm_persist, dim3(256), dim3(256), args, 0, stream);
}